// Round 20
// baseline (438.378 us; speedup 1.0000x reference)
//
#include <hip/hip_runtime.h>
#include <hip/hip_bf16.h>

// Problem constants
#define BDIM 1024
#define ROI 200
#define DIN 200
#define NSUB 8
#define NROWS (BDIM * ROI)           // 204800
#define XELEMS ((size_t)NROWS * 200) // 40,960,000
#define PLPAD 32
#define PLSZ (XELEMS + PLPAD)

typedef __attribute__((ext_vector_type(8))) short short8;
typedef __attribute__((ext_vector_type(4))) float f32x4;

__device__ __constant__ float d_invcnt[8] = {
    1.f/41.f, 1.f/29.f, 1.f/21.f, 1.f/19.f, 1.f/20.f, 1.f/7.f, 1.f/21.f, 1.f/42.f};

__device__ inline unsigned short f2bf_rn(float x) {
  unsigned u = __float_as_uint(x);
  return (unsigned short)((u + 0x7FFFu + ((u >> 16) & 1u)) >> 16);
}
__device__ constexpr int seg_of_c(int r) {
  return (r < 41) ? 0 : (r < 70) ? 1 : (r < 91) ? 2 : (r < 110) ? 3
       : (r < 130) ? 4 : (r < 137) ? 5 : (r < 158) ? 6 : 7;
}

// async global->LDS, 16B per lane; LDS dest = wave-uniform base + lane*16
__device__ inline void gload_lds16(const unsigned short* src, unsigned short* dst) {
  __builtin_amdgcn_global_load_lds(
      (const __attribute__((address_space(1))) void*)src,
      (__attribute__((address_space(3))) void*)dst, 16, 0, 0);
}

// Merged rs_intra rowsum (one wave/row) + rs_inter sums (tail blocks)
__global__ __launch_bounds__(256) void rowint_k(const float* __restrict__ intra,
                                                const float* __restrict__ inter,
                                                float* __restrict__ rsI,
                                                float* __restrict__ rsP) {
  if (blockIdx.x < NROWS / 4) {
    int row = blockIdx.x * 4 + (threadIdx.x >> 6);
    int lane = threadIdx.x & 63;
    const float* p = intra + (size_t)row * 200;
    float v = p[lane] + p[lane + 64] + p[lane + 128];
    if (lane < 8) v += p[lane + 192];
    #pragma unroll
    for (int off = 32; off > 0; off >>= 1) v += __shfl_down(v, off);
    if (lane == 0) rsI[row] = v;
  } else {
    int i = (blockIdx.x - NROWS / 4) * 256 + threadIdx.x;
    if (i < BDIM * NSUB) {
      const float* p = inter + (size_t)i * 8;
      float v = 0.f;
      #pragma unroll
      for (int c = 0; c < 8; ++c) v += p[c];
      rsP[i] = v;
    }
  }
}

// seg_combine, fp32 input, no BN (block 1) — two-pass (160KB won't fit LDS)
__global__ __launch_bounds__(128) void seg_combine_f32_k(
    const float* __restrict__ xf, const float* __restrict__ rsI,
    const float* __restrict__ rsP, unsigned short* __restrict__ yp) {
  int b = blockIdx.x;
  int t = threadIdx.x;
  if (t >= 100) return;
  int c0 = 2 * t;
  size_t base = (size_t)b * 40000 + c0;
  float a0[8] = {0,0,0,0,0,0,0,0};
  float a1[8] = {0,0,0,0,0,0,0,0};
  #pragma unroll
  for (int r = 0; r < 200; ++r) {
    float2 fv = *(const float2*)(xf + base + (size_t)r * 200);
    int s = seg_of_c(r);
    a0[s] += fv.x; a1[s] += fv.y;
  }
  float pr0[8], pr1[8];
  #pragma unroll
  for (int s = 0; s < 8; ++s) {
    float rp = rsP[b * 8 + s];
    pr0[s] = rp * a0[s] * d_invcnt[s];
    pr1[s] = rp * a1[s] * d_invcnt[s];
  }
  const float* rsIb = rsI + b * 200;
  #pragma unroll
  for (int r = 0; r < 200; ++r) {
    size_t idx = base + (size_t)r * 200;
    float2 fv = *(const float2*)(xf + idx);
    int s = seg_of_c(r);
    float ri = rsIb[r];
    float y0 = 0.5f * (ri * fv.x + pr0[s]);
    float y1 = 0.5f * (ri * fv.y + pr1[s]);
    *(unsigned*)(yp + idx) = (unsigned)f2bf_rn(y0) | ((unsigned)f2bf_rn(y1) << 16);
  }
}

// Single-pass seg_combine (bf16 plane input) with LDS staging + inline BN.
// One batch (200x200 bf16 = 80KB) staged to LDS via global_load_lds; both
// phases read LDS. 256 thr (staging: all 4 waves; compute: t<100).
__global__ __launch_bounds__(256, 2) void seg_combine_bn2_k(
    const unsigned short* __restrict__ xp, const float* __restrict__ rsI,
    const float* __restrict__ rsP, const float* __restrict__ stats,
    const float* __restrict__ g, const float* __restrict__ be,
    unsigned short* __restrict__ yp) {
  __shared__ unsigned short xs[40000];   // 80,000 B
  const float invN = 1.f / (float)NROWS;
  int b = blockIdx.x;
  int tid = threadIdx.x;
  int lane = tid & 63;
  int wid = tid >> 6;
  const unsigned short* src = xp + (size_t)b * 40000;
  // stage: 5000 granules of 16B, linear
  for (int g0 = wid * 64; g0 < 5000; g0 += 256) {
    int s = g0 + lane;
    if (s < 5000)
      gload_lds16(src + (size_t)s * 8, &xs[(size_t)g0 * 8]);
  }
  __syncthreads();  // drains vmcnt: batch resident in LDS

  int t = tid;
  if (t < 100) {
    int c0 = 2 * t;
    float m0 = stats[c0] * invN;
    float va0 = stats[200 + c0] * invN - m0 * m0;
    float sc0 = rsqrtf(va0 + 1e-5f) * g[c0];
    float sh0 = be[c0] - m0 * sc0;
    float m1 = stats[c0 + 1] * invN;
    float va1 = stats[200 + c0 + 1] * invN - m1 * m1;
    float sc1 = rsqrtf(va1 + 1e-5f) * g[c0 + 1];
    float sh1 = be[c0 + 1] - m1 * sc1;
    float a0[8] = {0,0,0,0,0,0,0,0};
    float a1[8] = {0,0,0,0,0,0,0,0};
    #pragma unroll
    for (int r = 0; r < 200; ++r) {
      unsigned u = *(const unsigned*)&xs[r * 200 + c0];
      int s = seg_of_c(r);
      a0[s] += __uint_as_float(u << 16);
      a1[s] += __uint_as_float(u & 0xFFFF0000u);
    }
    float pr0[8], pr1[8];
    #pragma unroll
    for (int s = 0; s < 8; ++s) {
      float mm0 = a0[s] * d_invcnt[s] * sc0 + sh0;
      float mm1 = a1[s] * d_invcnt[s] * sc1 + sh1;
      float rp = rsP[b * 8 + s];
      pr0[s] = rp * mm0; pr1[s] = rp * mm1;
    }
    const float* rsIb = rsI + b * 200;
    size_t base = (size_t)b * 40000 + c0;
    #pragma unroll
    for (int r = 0; r < 200; ++r) {
      unsigned u = *(const unsigned*)&xs[r * 200 + c0];
      float v0 = __uint_as_float(u << 16) * sc0 + sh0;
      float v1 = __uint_as_float(u & 0xFFFF0000u) * sc1 + sh1;
      int s = seg_of_c(r);
      float ri = rsIb[r];
      float y0 = 0.5f * (ri * v0 + pr0[s]);
      float y1 = 0.5f * (ri * v1 + pr1[s]);
      *(unsigned*)(yp + base + (size_t)r * 200) =
          (unsigned)f2bf_rn(y0) | ((unsigned)f2bf_rn(y1) << 16);
    }
  }
}

// One weight conversion element (fragment-major granule layout)
__device__ inline void wconv_one(const float* __restrict__ W, int K, int N,
                                 int NFRAG, int KSTEPS, int idx,
                                 unsigned short* __restrict__ dst) {
  int j = idx & 7;
  int lane = (idx >> 3) & 63;
  int rest = idx >> 9;
  int frag = rest % NFRAG;
  int rest2 = rest / NFRAG;
  int ks = rest2 % KSTEPS;
  int cb = rest2 / KSTEPS;
  int k = ks * 32 + ((lane >> 4) << 3) + j;
  int col = cb * NFRAG * 16 + frag * 16 + (lane & 15);
  float v = (k < K && col < N) ? W[(size_t)k * N + col] : 0.f;
  dst[idx] = f2bf_rn(v);
}

// All five weight conversions in one launch (linear id over 5 regions)
__global__ __launch_bounds__(256) void wconv_all_k(
    const float* __restrict__ W0, const float* __restrict__ W1,
    const float* __restrict__ W2, const float* __restrict__ W3,
    const float* __restrict__ W4,
    unsigned short* __restrict__ w0f, unsigned short* __restrict__ w1f,
    unsigned short* __restrict__ w2f, unsigned short* __restrict__ w3f,
    unsigned short* __restrict__ w4f) {
  const int R = 50176;           // 2*7*7*64*8
  const int R3 = 14336;          // 1*7*4*64*8
  const int R4 = 1024;           // 1*2*1*64*8
  int id = blockIdx.x * 256 + threadIdx.x;
  if (id < R)                    wconv_one(W0, 200, 200, 7, 7, id, w0f);
  else if (id < 2 * R)           wconv_one(W1, 200, 200, 7, 7, id - R, w1f);
  else if (id < 3 * R)           wconv_one(W2, 200, 200, 7, 7, id - 2 * R, w2f);
  else if (id < 3 * R + R3)      wconv_one(W3, 200, 64, 4, 7, id - 3 * R, w3f);
  else if (id < 3 * R + R3 + R4) wconv_one(W4, 64, 8, 1, 2, id - 3 * R - R3, w4f);
}

// Barrier-free per-wave async-LDS streaming GEMM (unchanged).
template<int ACT, int STATS>
__global__ __launch_bounds__(512, 1) void gemm_bf3_k(
    const unsigned short* __restrict__ A, const unsigned short* __restrict__ Wf,
    const float* __restrict__ bias, unsigned short* __restrict__ Cp,
    float* __restrict__ stats) {
  constexpr int G = 7 * 7 * 64;
  __shared__ unsigned short wlds[G * 8];
  __shared__ unsigned short abuf[8][2][400 * 8];
  __shared__ float s_sum[112];
  __shared__ float s_sq[112];
  int tid = threadIdx.x;
  int lane = tid & 63;
  int wid = tid >> 6;
  int cb = blockIdx.y;

  const unsigned short* wsrc = Wf + (size_t)cb * G * 8;
  for (int g0 = wid * 64; g0 < G; g0 += 512)
    gload_lds16(wsrc + (size_t)(g0 + lane) * 8, &wlds[(size_t)g0 * 8]);
  if (STATS && tid < 112) { s_sum[tid] = 0.f; s_sq[tid] = 0.f; }

  int gw = blockIdx.x * 8 + wid;
  const int stride = 1024, nt = 12800;
  int row = lane & 15;
  int laneg = lane >> 4;

  auto issue_tile = [&](int t, unsigned short* buf) {
    const unsigned short* src = A + (size_t)t * 3200;
    #pragma unroll
    for (int j = 0; j < 7; ++j) {
      int slot = j * 64 + lane;
      if (slot < 400)
        gload_lds16(src + (size_t)slot * 8, buf + (size_t)j * 512);
    }
  };

  issue_tile(gw, &abuf[wid][0][0]);
  issue_tile(gw + stride, &abuf[wid][1][0]);
  __syncthreads();

  float lsum[7], lsq[7];
  #pragma unroll
  for (int f = 0; f < 7; ++f) { lsum[f] = 0.f; lsq[f] = 0.f; }
  int colbase = cb * 112;

  for (int i = 0; ; ++i) {
    int t = gw + i * stride;
    if (t >= nt) break;
    if (i) {
      asm volatile("s_waitcnt vmcnt(47)" ::: "memory");
      __builtin_amdgcn_sched_barrier(0);
    }
    const unsigned short* ab = &abuf[wid][i & 1][0];
    short8 av[7];
    #pragma unroll
    for (int ks = 0; ks < 7; ++ks) {
      int cs = ks * 4 + laneg;
      if (cs > 24) cs = 0;
      av[ks] = *(const short8*)&ab[(size_t)(row * 25 + cs) * 8];
    }
    asm volatile("s_waitcnt lgkmcnt(0)" ::: "memory");
    __builtin_amdgcn_sched_barrier(0);
    {
      int t2 = t + 2 * stride;
      issue_tile(t2 < nt ? t2 : gw, &abuf[wid][i & 1][0]);
    }
    __builtin_amdgcn_sched_barrier(0);
    f32x4 acc[7];
    #pragma unroll
    for (int f = 0; f < 7; ++f) acc[f] = 0.0f;
    #pragma unroll
    for (int ks = 0; ks < 7; ++ks) {
      const short8* wp = (const short8*)wlds + (size_t)(ks * 7) * 64 + lane;
      #pragma unroll
      for (int f = 0; f < 7; ++f) {
        short8 wv = wp[(size_t)f * 64];
        acc[f] = __builtin_amdgcn_mfma_f32_16x16x32_bf16(av[ks], wv, acc[f], 0, 0, 0);
      }
    }
    int row0 = t * 16 + laneg * 4;
    #pragma unroll
    for (int f = 0; f < 7; ++f) {
      int col = colbase + f * 16 + row;
      if (col < 200) {
        float b = bias[col];
        #pragma unroll
        for (int r = 0; r < 4; ++r) {
          float v = acc[f][r] + b;
          if (ACT) v = (v >= 0.f) ? v : 0.2f * v;
          Cp[(size_t)(row0 + r) * 200 + col] = f2bf_rn(v);
          if (STATS) { lsum[f] += v; lsq[f] += v * v; }
        }
      }
    }
    __builtin_amdgcn_sched_barrier(0);
  }

  if (STATS) {
    #pragma unroll
    for (int f = 0; f < 7; ++f) {
      float s = lsum[f] + __shfl_xor(lsum[f], 16);
      s += __shfl_xor(s, 32);
      float q = lsq[f] + __shfl_xor(lsq[f], 16);
      q += __shfl_xor(q, 32);
      if (laneg == 0) {
        atomicAdd(&s_sum[f * 16 + row], s);
        atomicAdd(&s_sq[f * 16 + row], q);
      }
    }
    __syncthreads();
    if (tid < 112) {
      int col = colbase + tid;
      if (col < 200) {
        atomicAdd(&stats[col], s_sum[tid]);
        atomicAdd(&stats[200 + col], s_sq[tid]);
      }
    }
  }
}

// Streaming fused W3+W4 (unchanged).
__global__ __launch_bounds__(512, 1) void gemm_w34s_k(
    const unsigned short* __restrict__ A, const unsigned short* __restrict__ W3f,
    const unsigned short* __restrict__ W4f, const float* __restrict__ b3,
    const float* __restrict__ b4, unsigned short* __restrict__ xcls) {
  __shared__ unsigned short w3lds[1792 * 8];
  __shared__ unsigned short w4lds[128 * 8];
  __shared__ unsigned short abuf[8][2][400 * 8];
  __shared__ unsigned short h3buf[8][16][72];
  int tid = threadIdx.x;
  int lane = tid & 63;
  int wid = tid >> 6;

  for (int g0 = wid * 64; g0 < 1792; g0 += 512)
    gload_lds16(W3f + (size_t)(g0 + lane) * 8, &w3lds[(size_t)g0 * 8]);
  if (wid == 0)
    for (int g0 = 0; g0 < 128; g0 += 64)
      gload_lds16(W4f + (size_t)(g0 + lane) * 8, &w4lds[(size_t)g0 * 8]);

  int gw = blockIdx.x * 8 + wid;
  const int stride = 1024, nt = 12800;
  int row = lane & 15;
  int laneg = lane >> 4;

  auto issue_tile = [&](int t, unsigned short* buf) {
    const unsigned short* src = A + (size_t)t * 3200;
    #pragma unroll
    for (int j = 0; j < 7; ++j) {
      int slot = j * 64 + lane;
      if (slot < 400)
        gload_lds16(src + (size_t)slot * 8, buf + (size_t)j * 512);
    }
  };

  issue_tile(gw, &abuf[wid][0][0]);
  issue_tile(gw + stride, &abuf[wid][1][0]);
  __syncthreads();

  for (int i = 0; ; ++i) {
    int t = gw + i * stride;
    if (t >= nt) break;
    if (i) {
      asm volatile("s_waitcnt vmcnt(15)" ::: "memory");
      __builtin_amdgcn_sched_barrier(0);
    }
    const unsigned short* ab = &abuf[wid][i & 1][0];
    short8 av[7];
    #pragma unroll
    for (int ks = 0; ks < 7; ++ks) {
      int cs = ks * 4 + laneg;
      if (cs > 24) cs = 0;
      av[ks] = *(const short8*)&ab[(size_t)(row * 25 + cs) * 8];
    }
    asm volatile("s_waitcnt lgkmcnt(0)" ::: "memory");
    __builtin_amdgcn_sched_barrier(0);
    {
      int t2 = t + 2 * stride;
      issue_tile(t2 < nt ? t2 : gw, &abuf[wid][i & 1][0]);
    }
    __builtin_amdgcn_sched_barrier(0);
    f32x4 acc[4];
    #pragma unroll
    for (int f = 0; f < 4; ++f) acc[f] = 0.0f;
    #pragma unroll
    for (int ks = 0; ks < 7; ++ks) {
      const short8* wp = (const short8*)w3lds + (size_t)(ks * 4) * 64 + lane;
      #pragma unroll
      for (int f = 0; f < 4; ++f) {
        short8 wv = wp[(size_t)f * 64];
        acc[f] = __builtin_amdgcn_mfma_f32_16x16x32_bf16(av[ks], wv, acc[f], 0, 0, 0);
      }
    }
    int r0 = laneg * 4;
    #pragma unroll
    for (int f = 0; f < 4; ++f) {
      int col = f * 16 + row;
      float bb = b3[col];
      #pragma unroll
      for (int r = 0; r < 4; ++r) {
        float v = acc[f][r] + bb;
        v = (v >= 0.f) ? v : 0.2f * v;
        h3buf[wid][r0 + r][col] = f2bf_rn(v);
      }
    }
    f32x4 acc2 = 0.0f;
    #pragma unroll
    for (int ks = 0; ks < 2; ++ks) {
      short8 a2 = *(const short8*)&h3buf[wid][row][ks * 32 + laneg * 8];
      short8 wv = *(const short8*)&w4lds[(size_t)(ks * 64 + lane) * 8];
      acc2 = __builtin_amdgcn_mfma_f32_16x16x32_bf16(a2, wv, acc2, 0, 0, 0);
    }
    int col = lane & 15;
    if (col < 8) {
      float bb = b4[col];
      #pragma unroll
      for (int r = 0; r < 4; ++r) {
        int rr = t * 16 + r0 + r;
        float v = acc2[r] + bb;
        v = (v >= 0.f) ? v : 0.2f * v;
        xcls[(size_t)(rr / 200) * 1600 + (rr % 200) * 8 + col] = f2bf_rn(v);
      }
    }
    __builtin_amdgcn_sched_barrier(0);
  }
}

// bn3d stats over bf16 xcls (1024 x 1600; r = col>>3)
__global__ __launch_bounds__(256) void bn3d_stats_bf_k(const unsigned short* __restrict__ x,
                                                       float* __restrict__ stats) {
  int t = threadIdx.x;
  if (t >= 200) return;
  const unsigned short* p = x + (size_t)blockIdx.x * 16 * 1600 + t * 8;
  float s = 0.f, q = 0.f;
  for (int b = 0; b < 16; ++b) {
    const unsigned* u = (const unsigned*)(p + (size_t)b * 1600);
    #pragma unroll
    for (int i = 0; i < 4; ++i) {
      unsigned w = u[i];
      float v0 = __uint_as_float(w << 16);
      float v1 = __uint_as_float(w & 0xFFFF0000u);
      s += v0 + v1;
      q += v0 * v0 + v1 * v1;
    }
  }
  atomicAdd(&stats[t], s);
  atomicAdd(&stats[200 + t], q);
}

// Wc1 fold (BN3d scale computed inline) + fragment-major bf16 conversion.
__global__ __launch_bounds__(256) void wcls_conv_k(const float* __restrict__ Wc1,
                                                   const float* __restrict__ stats,
                                                   const float* __restrict__ g3,
                                                   unsigned short* __restrict__ dst) {
  const float invN = 1.f / 8192.f;
  int idx = blockIdx.x * 256 + threadIdx.x;
  if (idx >= 409600) return;
  int j = idx & 7;
  int lane = (idx >> 3) & 63;
  int rest = idx >> 9;
  int frag = rest & 3;
  int rest2 = rest >> 2;
  int ks = rest2 % 10;
  int slice = rest2 / 10;
  int kc = slice % 5, cb = slice / 5;
  int k = kc * 320 + ks * 32 + ((lane >> 4) << 3) + j;
  int col = cb * 64 + frag * 16 + (lane & 15);
  int r = k >> 3;
  float m = stats[r] * invN;
  float var = stats[200 + r] * invN - m * m;
  float scv = rsqrtf(var + 1e-5f) * g3[r];
  dst[idx] = f2bf_rn(Wc1[(size_t)k * 256 + col] * scv);
}

// bias1p += sum_k sh[k>>3] * Wc1[k][n], sh computed inline (bc1 added in cls2)
__global__ __launch_bounds__(256) void bias1_acc_k(const float* __restrict__ Wc1,
                                                   const float* __restrict__ stats,
                                                   const float* __restrict__ g3,
                                                   const float* __restrict__ be3,
                                                   float* __restrict__ bias1p) {
  const float invN = 1.f / 8192.f;
  int t = threadIdx.x;
  int k0 = blockIdx.x * 100;
  float a = 0.f;
  #pragma unroll 4
  for (int k = k0; k < k0 + 100; ++k) {
    int r = k >> 3;
    float m = stats[r] * invN;
    float var = stats[200 + r] * invN - m * m;
    float scv = rsqrtf(var + 1e-5f) * g3[r];
    float sh = be3[r] - m * scv;
    a += sh * Wc1[(size_t)k * 256 + t];
  }
  atomicAdd(&bias1p[t], a);
}

// Classifier GEMM1 (MFMA, K-split atomics), unchanged.
__global__ __launch_bounds__(256, 3) void gemm_cls1_k(
    const unsigned short* __restrict__ xcls, const unsigned short* __restrict__ Wf,
    float* __restrict__ h1f) {
  __shared__ unsigned short wlds[10 * 4 * 64 * 8];
  int tid = threadIdx.x;
  int lane = tid & 63;
  int wid = tid >> 6;
  const unsigned short* wsrc = Wf + (size_t)(blockIdx.y * 5 + blockIdx.z) * (10 * 4 * 64) * 8;
  for (int g0 = wid * 64; g0 < 2560; g0 += 256)
    gload_lds16(wsrc + (size_t)(g0 + lane) * 8, &wlds[(size_t)g0 * 8]);

  int row0 = blockIdx.x * 128 + wid * 32;
  int kbase = blockIdx.z * 320;
  const unsigned short* pA = xcls + (size_t)(row0 + (lane & 15)) * 1600 + kbase + ((lane >> 4) << 3);
  const unsigned short* pB = pA + 16 * 1600;
  short8 aA[10], aB[10];
  #pragma unroll
  for (int i = 0; i < 10; ++i) {
    aA[i] = *(const short8*)(pA + i * 32);
    aB[i] = *(const short8*)(pB + i * 32);
  }
  __builtin_amdgcn_sched_barrier(0);
  __syncthreads();

  f32x4 accA[4], accB[4];
  #pragma unroll
  for (int f = 0; f < 4; ++f) { accA[f] = 0.0f; accB[f] = 0.0f; }
  #pragma unroll
  for (int ks = 0; ks < 10; ++ks) {
    const short8* wp = (const short8*)wlds + (size_t)(ks * 4) * 64 + lane;
    #pragma unroll
    for (int f = 0; f < 4; ++f) {
      short8 wv = wp[(size_t)f * 64];
      accA[f] = __builtin_amdgcn_mfma_f32_16x16x32_bf16(aA[ks], wv, accA[f], 0, 0, 0);
      accB[f] = __builtin_amdgcn_mfma_f32_16x16x32_bf16(aB[ks], wv, accB[f], 0, 0, 0);
    }
  }
  int colbase = blockIdx.y * 64;
  int r0 = (lane >> 4) * 4;
  #pragma unroll
  for (int f = 0; f < 4; ++f) {
    int col = colbase + f * 16 + (lane & 15);
    #pragma unroll
    for (int r = 0; r < 4; ++r) {
      atomicAdd(&h1f[(size_t)(row0 + r0 + r) * 256 + col], accA[f][r]);
      atomicAdd(&h1f[(size_t)(row0 + 16 + r0 + r) * 256 + col], accB[f][r]);
    }
  }
}

// Classifier tail: h1 = leaky(h1f + bias1p + bc1), -> Wc2 -> Wc3.
__global__ __launch_bounds__(256) void classifier2_k(
    const float* __restrict__ h1f, const float* __restrict__ bias1p,
    const float* __restrict__ bc1,
    const float* __restrict__ Wc2, const float* __restrict__ bc2,
    const float* __restrict__ Wc3, const float* __restrict__ bc3,
    float* __restrict__ out) {
  __shared__ float h1s[8][256];
  __shared__ float h2s[8][32];
  int t = threadIdx.x;
  int b0 = blockIdx.x * 8;
  float bsum = bias1p[t] + bc1[t];
  #pragma unroll
  for (int j = 0; j < 8; ++j) {
    float v = h1f[(size_t)(b0 + j) * 256 + t] + bsum;
    h1s[j][t] = (v >= 0.f) ? v : 0.2f * v;
  }
  __syncthreads();
  {
    int j = t >> 5, c = t & 31;
    float a = 0.f;
    #pragma unroll 8
    for (int k = 0; k < 256; ++k) a += h1s[j][k] * Wc2[k * 32 + c];
    float v = a + bc2[c];
    h2s[j][c] = (v >= 0.f) ? v : 0.2f * v;
  }
  __syncthreads();
  if (t < 16) {
    int j = t >> 1, c = t & 1;
    float a = 0.f;
    #pragma unroll
    for (int k = 0; k < 32; ++k) a += h2s[j][k] * Wc3[k * 2 + c];
    out[(size_t)(b0 + j) * 2 + c] = a + bc3[c];
  }
}

extern "C" void kernel_launch(void* const* d_in, const int* in_sizes, int n_in,
                              void* d_out, int out_size, void* d_ws, size_t ws_size,
                              hipStream_t stream) {
  const float* intra = (const float*)d_in[1];
  const float* inter = (const float*)d_in[2];
  const float* nodef = (const float*)d_in[3];
  const float* W0 = (const float*)d_in[4];
  const float* b0 = (const float*)d_in[5];
  const float* W1 = (const float*)d_in[6];
  const float* b1 = (const float*)d_in[7];
  const float* g1 = (const float*)d_in[8];
  const float* be1 = (const float*)d_in[9];
  const float* W2 = (const float*)d_in[10];
  const float* b2 = (const float*)d_in[11];
  const float* g2 = (const float*)d_in[12];
  const float* be2 = (const float*)d_in[13];
  const float* W3 = (const float*)d_in[14];
  const float* b3 = (const float*)d_in[15];
  const float* W4 = (const float*)d_in[16];
  const float* b4 = (const float*)d_in[17];
  const float* g3 = (const float*)d_in[18];
  const float* be3 = (const float*)d_in[19];
  const float* Wc1 = (const float*)d_in[20];
  const float* bc1 = (const float*)d_in[21];
  const float* Wc2 = (const float*)d_in[22];
  const float* bc2 = (const float*)d_in[23];
  const float* Wc3 = (const float*)d_in[24];
  const float* bc3 = (const float*)d_in[25];
  float* out = (float*)d_out;

  // Layout: 2 bf16 planes (ping-pong), then fp32 scratch + weights.
  unsigned short* P0 = (unsigned short*)d_ws;
  unsigned short* P1 = P0 + PLSZ;
  float* fbase = (float*)(P1 + PLSZ);
  float* rsI   = fbase;                        // 204,800
  float* rsP   = rsI + NROWS;                  // 8,192
  float* statsA = rsP + BDIM * 8;              // 4 x 512 slots
  float* stats0 = statsA;
  float* stats1 = statsA + 512;
  float* stats2 = statsA + 1024;
  float* bias1p = statsA + 2048;               // 512
  float* h1f    = bias1p + 512;                // 262,144
  unsigned short* wt = (unsigned short*)(h1f + (size_t)BDIM * 256);
  const size_t W200SZ = 2 * 7 * 7 * 64 * 8;    // 50,176 shorts
  const size_t W3SZ   = 1 * 7 * 4 * 64 * 8;    // 14,336 shorts
  const size_t W4SZ   = 1 * 2 * 1 * 64 * 8;    // 1,024 shorts
  unsigned short* w0f = wt;
  unsigned short* w1f = w0f + W200SZ;
  unsigned short* w2f = w1f + W200SZ;
  unsigned short* w3f = w2f + W200SZ;
  unsigned short* w4f = w3f + W3SZ;
  unsigned short* wc1f = w4f + W4SZ;
  unsigned short* xcls = P0;   // aliases P0 (dead at that point)

  // single consolidated zeroing: stats x4 + bias1p + h1f (contiguous)
  hipMemsetAsync(statsA, 0, (2048 + 512 + (size_t)BDIM * 256) * sizeof(float), stream);

  // all weight conversions in one launch
  wconv_all_k<<<648, 256, 0, stream>>>(W0, W1, W2, W3, W4, w0f, w1f, w2f, w3f, w4f);

  // row sums (intra) + inter sums merged
  rowint_k<<<NROWS / 4 + 32, 256, 0, stream>>>(intra, inter, rsI, rsP);

  // block 1: nodef (fp32) -> X1 (P0)
  seg_combine_f32_k<<<BDIM, 128, 0, stream>>>(nodef, rsI, rsP, P0);

  // H = leaky(X1@W0+b0): P0 -> P1
  gemm_bf3_k<1, 0><<<dim3(128, 2), 512, 0, stream>>>(P0, w0f, b0, P1, nullptr);
  // Y1 = H@W1+b1 (+stats0): P1 -> P0
  gemm_bf3_k<0, 1><<<dim3(128, 2), 512, 0, stream>>>(P1, w1f, b1, P0, stats0);

  // block 2 (BN1 inline, single-pass LDS): P0 -> X2 (P1)
  seg_combine_bn2_k<<<BDIM, 256, 0, stream>>>(P0, rsI, rsP, stats0, g1, be1, P1);

  // Y2 = leaky(X2@W2+b2) (+stats1): P1 -> P0
  gemm_bf3_k<1, 1><<<dim3(128, 2), 512, 0, stream>>>(P1, w2f, b2, P0, stats1);

  // block 3 (BN2 inline, single-pass LDS): P0 -> X3 (P1)
  seg_combine_bn2_k<<<BDIM, 256, 0, stream>>>(P0, rsI, rsP, stats1, g2, be2, P1);

  // xcls = leaky(leaky(X3@W3+b3)@W4+b4): P1 -> xcls
  gemm_w34s_k<<<128, 512, 0, stream>>>(P1, w3f, w4f, b3, b4, xcls);

  // bn3d stats on xcls -> stats2; affine folded into Wc1/bias1 inline
  bn3d_stats_bf_k<<<64, 256, 0, stream>>>(xcls, stats2);
  wcls_conv_k<<<1600, 256, 0, stream>>>(Wc1, stats2, g3, wc1f);
  bias1_acc_k<<<16, 256, 0, stream>>>(Wc1, stats2, g3, be3, bias1p);

  // classifier GEMM1 (K-split atomics into pre-zeroed h1f) then tail
  gemm_cls1_k<<<dim3(8, 4, 5), 256, 0, stream>>>(xcls, wc1f, h1f);
  classifier2_k<<<BDIM / 8, 256, 0, stream>>>(h1f, bias1p, bc1, Wc2, bc2, Wc3, bc3, out);
}

// Round 21
// 406.846 us; speedup vs baseline: 1.0775x; 1.0775x over previous
//
#include <hip/hip_runtime.h>
#include <hip/hip_bf16.h>

// Problem constants
#define BDIM 1024
#define ROI 200
#define DIN 200
#define NSUB 8
#define NROWS (BDIM * ROI)           // 204800
#define XELEMS ((size_t)NROWS * 200) // 40,960,000
#define PLPAD 32
#define PLSZ (XELEMS + PLPAD)

typedef __attribute__((ext_vector_type(8))) short short8;
typedef __attribute__((ext_vector_type(4))) float f32x4;

__device__ __constant__ float d_invcnt[8] = {
    1.f/41.f, 1.f/29.f, 1.f/21.f, 1.f/19.f, 1.f/20.f, 1.f/7.f, 1.f/21.f, 1.f/42.f};

__device__ inline unsigned short f2bf_rn(float x) {
  unsigned u = __float_as_uint(x);
  return (unsigned short)((u + 0x7FFFu + ((u >> 16) & 1u)) >> 16);
}
__device__ constexpr int seg_of_c(int r) {
  return (r < 41) ? 0 : (r < 70) ? 1 : (r < 91) ? 2 : (r < 110) ? 3
       : (r < 130) ? 4 : (r < 137) ? 5 : (r < 158) ? 6 : 7;
}

// async global->LDS, 16B per lane; LDS dest = wave-uniform base + lane*16
__device__ inline void gload_lds16(const unsigned short* src, unsigned short* dst) {
  __builtin_amdgcn_global_load_lds(
      (const __attribute__((address_space(1))) void*)src,
      (__attribute__((address_space(3))) void*)dst, 16, 0, 0);
}

// Merged rs_intra rowsum (one wave/row) + rs_inter sums (tail blocks)
__global__ __launch_bounds__(256) void rowint_k(const float* __restrict__ intra,
                                                const float* __restrict__ inter,
                                                float* __restrict__ rsI,
                                                float* __restrict__ rsP) {
  if (blockIdx.x < NROWS / 4) {
    int row = blockIdx.x * 4 + (threadIdx.x >> 6);
    int lane = threadIdx.x & 63;
    const float* p = intra + (size_t)row * 200;
    float v = p[lane] + p[lane + 64] + p[lane + 128];
    if (lane < 8) v += p[lane + 192];
    #pragma unroll
    for (int off = 32; off > 0; off >>= 1) v += __shfl_down(v, off);
    if (lane == 0) rsI[row] = v;
  } else {
    int i = (blockIdx.x - NROWS / 4) * 256 + threadIdx.x;
    if (i < BDIM * NSUB) {
      const float* p = inter + (size_t)i * 8;
      float v = 0.f;
      #pragma unroll
      for (int c = 0; c < 8; ++c) v += p[c];
      rsP[i] = v;
    }
  }
}

// seg_combine, fp32 input, no BN (block 1)
__global__ __launch_bounds__(128) void seg_combine_f32_k(
    const float* __restrict__ xf, const float* __restrict__ rsI,
    const float* __restrict__ rsP, unsigned short* __restrict__ yp) {
  int b = blockIdx.x;
  int t = threadIdx.x;
  if (t >= 100) return;
  int c0 = 2 * t;
  size_t base = (size_t)b * 40000 + c0;
  float a0[8] = {0,0,0,0,0,0,0,0};
  float a1[8] = {0,0,0,0,0,0,0,0};
  #pragma unroll
  for (int r = 0; r < 200; ++r) {
    float2 fv = *(const float2*)(xf + base + (size_t)r * 200);
    int s = seg_of_c(r);
    a0[s] += fv.x; a1[s] += fv.y;
  }
  float pr0[8], pr1[8];
  #pragma unroll
  for (int s = 0; s < 8; ++s) {
    float rp = rsP[b * 8 + s];
    pr0[s] = rp * a0[s] * d_invcnt[s];
    pr1[s] = rp * a1[s] * d_invcnt[s];
  }
  const float* rsIb = rsI + b * 200;
  #pragma unroll
  for (int r = 0; r < 200; ++r) {
    size_t idx = base + (size_t)r * 200;
    float2 fv = *(const float2*)(xf + idx);
    int s = seg_of_c(r);
    float ri = rsIb[r];
    float y0 = 0.5f * (ri * fv.x + pr0[s]);
    float y1 = 0.5f * (ri * fv.y + pr1[s]);
    *(unsigned*)(yp + idx) = (unsigned)f2bf_rn(y0) | ((unsigned)f2bf_rn(y1) << 16);
  }
}

// seg_combine, bf16-plane input, BN fold computed INLINE from raw stats.
__global__ __launch_bounds__(128) void seg_combine_bn_k(
    const unsigned short* __restrict__ xp, const float* __restrict__ rsI,
    const float* __restrict__ rsP, const float* __restrict__ stats,
    const float* __restrict__ g, const float* __restrict__ be,
    unsigned short* __restrict__ yp) {
  const float invN = 1.f / (float)NROWS;
  int b = blockIdx.x;
  int t = threadIdx.x;
  if (t >= 100) return;
  int c0 = 2 * t;
  float m0 = stats[c0] * invN;
  float va0 = stats[200 + c0] * invN - m0 * m0;
  float sc0 = rsqrtf(va0 + 1e-5f) * g[c0];
  float sh0 = be[c0] - m0 * sc0;
  float m1 = stats[c0 + 1] * invN;
  float va1 = stats[200 + c0 + 1] * invN - m1 * m1;
  float sc1 = rsqrtf(va1 + 1e-5f) * g[c0 + 1];
  float sh1 = be[c0 + 1] - m1 * sc1;
  size_t base = (size_t)b * 40000 + c0;
  float a0[8] = {0,0,0,0,0,0,0,0};
  float a1[8] = {0,0,0,0,0,0,0,0};
  #pragma unroll
  for (int r = 0; r < 200; ++r) {
    unsigned u = *(const unsigned*)(xp + base + (size_t)r * 200);
    int s = seg_of_c(r);
    a0[s] += __uint_as_float(u << 16);
    a1[s] += __uint_as_float(u & 0xFFFF0000u);
  }
  float pr0[8], pr1[8];
  #pragma unroll
  for (int s = 0; s < 8; ++s) {
    float mm0 = a0[s] * d_invcnt[s] * sc0 + sh0;
    float mm1 = a1[s] * d_invcnt[s] * sc1 + sh1;
    float rp = rsP[b * 8 + s];
    pr0[s] = rp * mm0; pr1[s] = rp * mm1;
  }
  const float* rsIb = rsI + b * 200;
  #pragma unroll
  for (int r = 0; r < 200; ++r) {
    size_t idx = base + (size_t)r * 200;
    unsigned u = *(const unsigned*)(xp + idx);
    float v0 = __uint_as_float(u << 16) * sc0 + sh0;
    float v1 = __uint_as_float(u & 0xFFFF0000u) * sc1 + sh1;
    int s = seg_of_c(r);
    float ri = rsIb[r];
    float y0 = 0.5f * (ri * v0 + pr0[s]);
    float y1 = 0.5f * (ri * v1 + pr1[s]);
    *(unsigned*)(yp + idx) = (unsigned)f2bf_rn(y0) | ((unsigned)f2bf_rn(y1) << 16);
  }
}

// One weight conversion element (fragment-major granule layout)
__device__ inline void wconv_one(const float* __restrict__ W, int K, int N,
                                 int NFRAG, int KSTEPS, int idx,
                                 unsigned short* __restrict__ dst) {
  int j = idx & 7;
  int lane = (idx >> 3) & 63;
  int rest = idx >> 9;
  int frag = rest % NFRAG;
  int rest2 = rest / NFRAG;
  int ks = rest2 % KSTEPS;
  int cb = rest2 / KSTEPS;
  int k = ks * 32 + ((lane >> 4) << 3) + j;
  int col = cb * NFRAG * 16 + frag * 16 + (lane & 15);
  float v = (k < K && col < N) ? W[(size_t)k * N + col] : 0.f;
  dst[idx] = f2bf_rn(v);
}

// All five weight conversions in one launch (linear id over 5 regions)
__global__ __launch_bounds__(256) void wconv_all_k(
    const float* __restrict__ W0, const float* __restrict__ W1,
    const float* __restrict__ W2, const float* __restrict__ W3,
    const float* __restrict__ W4,
    unsigned short* __restrict__ w0f, unsigned short* __restrict__ w1f,
    unsigned short* __restrict__ w2f, unsigned short* __restrict__ w3f,
    unsigned short* __restrict__ w4f) {
  const int R = 50176;           // 2*7*7*64*8
  const int R3 = 14336;          // 1*7*4*64*8
  const int R4 = 1024;           // 1*2*1*64*8
  int id = blockIdx.x * 256 + threadIdx.x;
  if (id < R)                    wconv_one(W0, 200, 200, 7, 7, id, w0f);
  else if (id < 2 * R)           wconv_one(W1, 200, 200, 7, 7, id - R, w1f);
  else if (id < 3 * R)           wconv_one(W2, 200, 200, 7, 7, id - 2 * R, w2f);
  else if (id < 3 * R + R3)      wconv_one(W3, 200, 64, 4, 7, id - 3 * R, w3f);
  else if (id < 3 * R + R3 + R4) wconv_one(W4, 64, 8, 1, 2, id - 3 * R - R3, w4f);
}

// Barrier-free per-wave async-LDS streaming GEMM (unchanged).
template<int ACT, int STATS>
__global__ __launch_bounds__(512, 1) void gemm_bf3_k(
    const unsigned short* __restrict__ A, const unsigned short* __restrict__ Wf,
    const float* __restrict__ bias, unsigned short* __restrict__ Cp,
    float* __restrict__ stats) {
  constexpr int G = 7 * 7 * 64;
  __shared__ unsigned short wlds[G * 8];
  __shared__ unsigned short abuf[8][2][400 * 8];
  __shared__ float s_sum[112];
  __shared__ float s_sq[112];
  int tid = threadIdx.x;
  int lane = tid & 63;
  int wid = tid >> 6;
  int cb = blockIdx.y;

  const unsigned short* wsrc = Wf + (size_t)cb * G * 8;
  for (int g0 = wid * 64; g0 < G; g0 += 512)
    gload_lds16(wsrc + (size_t)(g0 + lane) * 8, &wlds[(size_t)g0 * 8]);
  if (STATS && tid < 112) { s_sum[tid] = 0.f; s_sq[tid] = 0.f; }

  int gw = blockIdx.x * 8 + wid;
  const int stride = 1024, nt = 12800;
  int row = lane & 15;
  int laneg = lane >> 4;

  auto issue_tile = [&](int t, unsigned short* buf) {
    const unsigned short* src = A + (size_t)t * 3200;
    #pragma unroll
    for (int j = 0; j < 7; ++j) {
      int slot = j * 64 + lane;
      if (slot < 400)
        gload_lds16(src + (size_t)slot * 8, buf + (size_t)j * 512);
    }
  };

  issue_tile(gw, &abuf[wid][0][0]);
  issue_tile(gw + stride, &abuf[wid][1][0]);
  __syncthreads();

  float lsum[7], lsq[7];
  #pragma unroll
  for (int f = 0; f < 7; ++f) { lsum[f] = 0.f; lsq[f] = 0.f; }
  int colbase = cb * 112;

  for (int i = 0; ; ++i) {
    int t = gw + i * stride;
    if (t >= nt) break;
    if (i) {
      asm volatile("s_waitcnt vmcnt(47)" ::: "memory");
      __builtin_amdgcn_sched_barrier(0);
    }
    const unsigned short* ab = &abuf[wid][i & 1][0];
    short8 av[7];
    #pragma unroll
    for (int ks = 0; ks < 7; ++ks) {
      int cs = ks * 4 + laneg;
      if (cs > 24) cs = 0;
      av[ks] = *(const short8*)&ab[(size_t)(row * 25 + cs) * 8];
    }
    asm volatile("s_waitcnt lgkmcnt(0)" ::: "memory");
    __builtin_amdgcn_sched_barrier(0);
    {
      int t2 = t + 2 * stride;
      issue_tile(t2 < nt ? t2 : gw, &abuf[wid][i & 1][0]);
    }
    __builtin_amdgcn_sched_barrier(0);
    f32x4 acc[7];
    #pragma unroll
    for (int f = 0; f < 7; ++f) acc[f] = 0.0f;
    #pragma unroll
    for (int ks = 0; ks < 7; ++ks) {
      const short8* wp = (const short8*)wlds + (size_t)(ks * 7) * 64 + lane;
      #pragma unroll
      for (int f = 0; f < 7; ++f) {
        short8 wv = wp[(size_t)f * 64];
        acc[f] = __builtin_amdgcn_mfma_f32_16x16x32_bf16(av[ks], wv, acc[f], 0, 0, 0);
      }
    }
    int row0 = t * 16 + laneg * 4;
    #pragma unroll
    for (int f = 0; f < 7; ++f) {
      int col = colbase + f * 16 + row;
      if (col < 200) {
        float b = bias[col];
        #pragma unroll
        for (int r = 0; r < 4; ++r) {
          float v = acc[f][r] + b;
          if (ACT) v = (v >= 0.f) ? v : 0.2f * v;
          Cp[(size_t)(row0 + r) * 200 + col] = f2bf_rn(v);
          if (STATS) { lsum[f] += v; lsq[f] += v * v; }
        }
      }
    }
    __builtin_amdgcn_sched_barrier(0);
  }

  if (STATS) {
    #pragma unroll
    for (int f = 0; f < 7; ++f) {
      float s = lsum[f] + __shfl_xor(lsum[f], 16);
      s += __shfl_xor(s, 32);
      float q = lsq[f] + __shfl_xor(lsq[f], 16);
      q += __shfl_xor(q, 32);
      if (laneg == 0) {
        atomicAdd(&s_sum[f * 16 + row], s);
        atomicAdd(&s_sq[f * 16 + row], q);
      }
    }
    __syncthreads();
    if (tid < 112) {
      int col = colbase + tid;
      if (col < 200) {
        atomicAdd(&stats[col], s_sum[tid]);
        atomicAdd(&stats[200 + col], s_sq[tid]);
      }
    }
  }
}

// Streaming fused W3+W4 (unchanged).
__global__ __launch_bounds__(512, 1) void gemm_w34s_k(
    const unsigned short* __restrict__ A, const unsigned short* __restrict__ W3f,
    const unsigned short* __restrict__ W4f, const float* __restrict__ b3,
    const float* __restrict__ b4, unsigned short* __restrict__ xcls) {
  __shared__ unsigned short w3lds[1792 * 8];
  __shared__ unsigned short w4lds[128 * 8];
  __shared__ unsigned short abuf[8][2][400 * 8];
  __shared__ unsigned short h3buf[8][16][72];
  int tid = threadIdx.x;
  int lane = tid & 63;
  int wid = tid >> 6;

  for (int g0 = wid * 64; g0 < 1792; g0 += 512)
    gload_lds16(W3f + (size_t)(g0 + lane) * 8, &w3lds[(size_t)g0 * 8]);
  if (wid == 0)
    for (int g0 = 0; g0 < 128; g0 += 64)
      gload_lds16(W4f + (size_t)(g0 + lane) * 8, &w4lds[(size_t)g0 * 8]);

  int gw = blockIdx.x * 8 + wid;
  const int stride = 1024, nt = 12800;
  int row = lane & 15;
  int laneg = lane >> 4;

  auto issue_tile = [&](int t, unsigned short* buf) {
    const unsigned short* src = A + (size_t)t * 3200;
    #pragma unroll
    for (int j = 0; j < 7; ++j) {
      int slot = j * 64 + lane;
      if (slot < 400)
        gload_lds16(src + (size_t)slot * 8, buf + (size_t)j * 512);
    }
  };

  issue_tile(gw, &abuf[wid][0][0]);
  issue_tile(gw + stride, &abuf[wid][1][0]);
  __syncthreads();

  for (int i = 0; ; ++i) {
    int t = gw + i * stride;
    if (t >= nt) break;
    if (i) {
      asm volatile("s_waitcnt vmcnt(15)" ::: "memory");
      __builtin_amdgcn_sched_barrier(0);
    }
    const unsigned short* ab = &abuf[wid][i & 1][0];
    short8 av[7];
    #pragma unroll
    for (int ks = 0; ks < 7; ++ks) {
      int cs = ks * 4 + laneg;
      if (cs > 24) cs = 0;
      av[ks] = *(const short8*)&ab[(size_t)(row * 25 + cs) * 8];
    }
    asm volatile("s_waitcnt lgkmcnt(0)" ::: "memory");
    __builtin_amdgcn_sched_barrier(0);
    {
      int t2 = t + 2 * stride;
      issue_tile(t2 < nt ? t2 : gw, &abuf[wid][i & 1][0]);
    }
    __builtin_amdgcn_sched_barrier(0);
    f32x4 acc[4];
    #pragma unroll
    for (int f = 0; f < 4; ++f) acc[f] = 0.0f;
    #pragma unroll
    for (int ks = 0; ks < 7; ++ks) {
      const short8* wp = (const short8*)w3lds + (size_t)(ks * 4) * 64 + lane;
      #pragma unroll
      for (int f = 0; f < 4; ++f) {
        short8 wv = wp[(size_t)f * 64];
        acc[f] = __builtin_amdgcn_mfma_f32_16x16x32_bf16(av[ks], wv, acc[f], 0, 0, 0);
      }
    }
    int r0 = laneg * 4;
    #pragma unroll
    for (int f = 0; f < 4; ++f) {
      int col = f * 16 + row;
      float bb = b3[col];
      #pragma unroll
      for (int r = 0; r < 4; ++r) {
        float v = acc[f][r] + bb;
        v = (v >= 0.f) ? v : 0.2f * v;
        h3buf[wid][r0 + r][col] = f2bf_rn(v);
      }
    }
    f32x4 acc2 = 0.0f;
    #pragma unroll
    for (int ks = 0; ks < 2; ++ks) {
      short8 a2 = *(const short8*)&h3buf[wid][row][ks * 32 + laneg * 8];
      short8 wv = *(const short8*)&w4lds[(size_t)(ks * 64 + lane) * 8];
      acc2 = __builtin_amdgcn_mfma_f32_16x16x32_bf16(a2, wv, acc2, 0, 0, 0);
    }
    int col = lane & 15;
    if (col < 8) {
      float bb = b4[col];
      #pragma unroll
      for (int r = 0; r < 4; ++r) {
        int rr = t * 16 + r0 + r;
        float v = acc2[r] + bb;
        v = (v >= 0.f) ? v : 0.2f * v;
        xcls[(size_t)(rr / 200) * 1600 + (rr % 200) * 8 + col] = f2bf_rn(v);
      }
    }
    __builtin_amdgcn_sched_barrier(0);
  }
}

// bn3d stats over bf16 xcls (1024 x 1600; r = col>>3)
__global__ __launch_bounds__(256) void bn3d_stats_bf_k(const unsigned short* __restrict__ x,
                                                       float* __restrict__ stats) {
  int t = threadIdx.x;
  if (t >= 200) return;
  const unsigned short* p = x + (size_t)blockIdx.x * 16 * 1600 + t * 8;
  float s = 0.f, q = 0.f;
  for (int b = 0; b < 16; ++b) {
    const unsigned* u = (const unsigned*)(p + (size_t)b * 1600);
    #pragma unroll
    for (int i = 0; i < 4; ++i) {
      unsigned w = u[i];
      float v0 = __uint_as_float(w << 16);
      float v1 = __uint_as_float(w & 0xFFFF0000u);
      s += v0 + v1;
      q += v0 * v0 + v1 * v1;
    }
  }
  atomicAdd(&stats[t], s);
  atomicAdd(&stats[200 + t], q);
}

// Wc1 fold (BN3d scale computed inline) + fragment-major bf16 conversion.
__global__ __launch_bounds__(256) void wcls_conv_k(const float* __restrict__ Wc1,
                                                   const float* __restrict__ stats,
                                                   const float* __restrict__ g3,
                                                   unsigned short* __restrict__ dst) {
  const float invN = 1.f / 8192.f;
  int idx = blockIdx.x * 256 + threadIdx.x;
  if (idx >= 409600) return;
  int j = idx & 7;
  int lane = (idx >> 3) & 63;
  int rest = idx >> 9;
  int frag = rest & 3;
  int rest2 = rest >> 2;
  int ks = rest2 % 10;
  int slice = rest2 / 10;
  int kc = slice % 5, cb = slice / 5;
  int k = kc * 320 + ks * 32 + ((lane >> 4) << 3) + j;
  int col = cb * 64 + frag * 16 + (lane & 15);
  int r = k >> 3;
  float m = stats[r] * invN;
  float var = stats[200 + r] * invN - m * m;
  float scv = rsqrtf(var + 1e-5f) * g3[r];
  dst[idx] = f2bf_rn(Wc1[(size_t)k * 256 + col] * scv);
}

// bias1p += sum_k sh[k>>3] * Wc1[k][n], sh computed inline (bc1 added in cls2)
__global__ __launch_bounds__(256) void bias1_acc_k(const float* __restrict__ Wc1,
                                                   const float* __restrict__ stats,
                                                   const float* __restrict__ g3,
                                                   const float* __restrict__ be3,
                                                   float* __restrict__ bias1p) {
  const float invN = 1.f / 8192.f;
  int t = threadIdx.x;
  int k0 = blockIdx.x * 100;
  float a = 0.f;
  #pragma unroll 4
  for (int k = k0; k < k0 + 100; ++k) {
    int r = k >> 3;
    float m = stats[r] * invN;
    float var = stats[200 + r] * invN - m * m;
    float scv = rsqrtf(var + 1e-5f) * g3[r];
    float sh = be3[r] - m * scv;
    a += sh * Wc1[(size_t)k * 256 + t];
  }
  atomicAdd(&bias1p[t], a);
}

// Classifier GEMM1 (MFMA, K-split atomics), unchanged.
__global__ __launch_bounds__(256, 3) void gemm_cls1_k(
    const unsigned short* __restrict__ xcls, const unsigned short* __restrict__ Wf,
    float* __restrict__ h1f) {
  __shared__ unsigned short wlds[10 * 4 * 64 * 8];
  int tid = threadIdx.x;
  int lane = tid & 63;
  int wid = tid >> 6;
  const unsigned short* wsrc = Wf + (size_t)(blockIdx.y * 5 + blockIdx.z) * (10 * 4 * 64) * 8;
  for (int g0 = wid * 64; g0 < 2560; g0 += 256)
    gload_lds16(wsrc + (size_t)(g0 + lane) * 8, &wlds[(size_t)g0 * 8]);

  int row0 = blockIdx.x * 128 + wid * 32;
  int kbase = blockIdx.z * 320;
  const unsigned short* pA = xcls + (size_t)(row0 + (lane & 15)) * 1600 + kbase + ((lane >> 4) << 3);
  const unsigned short* pB = pA + 16 * 1600;
  short8 aA[10], aB[10];
  #pragma unroll
  for (int i = 0; i < 10; ++i) {
    aA[i] = *(const short8*)(pA + i * 32);
    aB[i] = *(const short8*)(pB + i * 32);
  }
  __builtin_amdgcn_sched_barrier(0);
  __syncthreads();

  f32x4 accA[4], accB[4];
  #pragma unroll
  for (int f = 0; f < 4; ++f) { accA[f] = 0.0f; accB[f] = 0.0f; }
  #pragma unroll
  for (int ks = 0; ks < 10; ++ks) {
    const short8* wp = (const short8*)wlds + (size_t)(ks * 4) * 64 + lane;
    #pragma unroll
    for (int f = 0; f < 4; ++f) {
      short8 wv = wp[(size_t)f * 64];
      accA[f] = __builtin_amdgcn_mfma_f32_16x16x32_bf16(aA[ks], wv, accA[f], 0, 0, 0);
      accB[f] = __builtin_amdgcn_mfma_f32_16x16x32_bf16(aB[ks], wv, accB[f], 0, 0, 0);
    }
  }
  int colbase = blockIdx.y * 64;
  int r0 = (lane >> 4) * 4;
  #pragma unroll
  for (int f = 0; f < 4; ++f) {
    int col = colbase + f * 16 + (lane & 15);
    #pragma unroll
    for (int r = 0; r < 4; ++r) {
      atomicAdd(&h1f[(size_t)(row0 + r0 + r) * 256 + col], accA[f][r]);
      atomicAdd(&h1f[(size_t)(row0 + 16 + r0 + r) * 256 + col], accB[f][r]);
    }
  }
}

// Classifier tail: h1 = leaky(h1f + bias1p + bc1), -> Wc2 -> Wc3.
__global__ __launch_bounds__(256) void classifier2_k(
    const float* __restrict__ h1f, const float* __restrict__ bias1p,
    const float* __restrict__ bc1,
    const float* __restrict__ Wc2, const float* __restrict__ bc2,
    const float* __restrict__ Wc3, const float* __restrict__ bc3,
    float* __restrict__ out) {
  __shared__ float h1s[8][256];
  __shared__ float h2s[8][32];
  int t = threadIdx.x;
  int b0 = blockIdx.x * 8;
  float bsum = bias1p[t] + bc1[t];
  #pragma unroll
  for (int j = 0; j < 8; ++j) {
    float v = h1f[(size_t)(b0 + j) * 256 + t] + bsum;
    h1s[j][t] = (v >= 0.f) ? v : 0.2f * v;
  }
  __syncthreads();
  {
    int j = t >> 5, c = t & 31;
    float a = 0.f;
    #pragma unroll 8
    for (int k = 0; k < 256; ++k) a += h1s[j][k] * Wc2[k * 32 + c];
    float v = a + bc2[c];
    h2s[j][c] = (v >= 0.f) ? v : 0.2f * v;
  }
  __syncthreads();
  if (t < 16) {
    int j = t >> 1, c = t & 1;
    float a = 0.f;
    #pragma unroll
    for (int k = 0; k < 32; ++k) a += h2s[j][k] * Wc3[k * 2 + c];
    out[(size_t)(b0 + j) * 2 + c] = a + bc3[c];
  }
}

extern "C" void kernel_launch(void* const* d_in, const int* in_sizes, int n_in,
                              void* d_out, int out_size, void* d_ws, size_t ws_size,
                              hipStream_t stream) {
  const float* intra = (const float*)d_in[1];
  const float* inter = (const float*)d_in[2];
  const float* nodef = (const float*)d_in[3];
  const float* W0 = (const float*)d_in[4];
  const float* b0 = (const float*)d_in[5];
  const float* W1 = (const float*)d_in[6];
  const float* b1 = (const float*)d_in[7];
  const float* g1 = (const float*)d_in[8];
  const float* be1 = (const float*)d_in[9];
  const float* W2 = (const float*)d_in[10];
  const float* b2 = (const float*)d_in[11];
  const float* g2 = (const float*)d_in[12];
  const float* be2 = (const float*)d_in[13];
  const float* W3 = (const float*)d_in[14];
  const float* b3 = (const float*)d_in[15];
  const float* W4 = (const float*)d_in[16];
  const float* b4 = (const float*)d_in[17];
  const float* g3 = (const float*)d_in[18];
  const float* be3 = (const float*)d_in[19];
  const float* Wc1 = (const float*)d_in[20];
  const float* bc1 = (const float*)d_in[21];
  const float* Wc2 = (const float*)d_in[22];
  const float* bc2 = (const float*)d_in[23];
  const float* Wc3 = (const float*)d_in[24];
  const float* bc3 = (const float*)d_in[25];
  float* out = (float*)d_out;

  // Layout: 2 bf16 planes (ping-pong), then fp32 scratch + weights.
  unsigned short* P0 = (unsigned short*)d_ws;
  unsigned short* P1 = P0 + PLSZ;
  float* fbase = (float*)(P1 + PLSZ);
  float* rsI   = fbase;                        // 204,800
  float* rsP   = rsI + NROWS;                  // 8,192
  float* statsA = rsP + BDIM * 8;              // 4 x 512 slots
  float* stats0 = statsA;
  float* stats1 = statsA + 512;
  float* stats2 = statsA + 1024;
  float* bias1p = statsA + 2048;               // 512
  float* h1f    = bias1p + 512;                // 262,144
  unsigned short* wt = (unsigned short*)(h1f + (size_t)BDIM * 256);
  const size_t W200SZ = 2 * 7 * 7 * 64 * 8;    // 50,176 shorts
  const size_t W3SZ   = 1 * 7 * 4 * 64 * 8;    // 14,336 shorts
  const size_t W4SZ   = 1 * 2 * 1 * 64 * 8;    // 1,024 shorts
  unsigned short* w0f = wt;
  unsigned short* w1f = w0f + W200SZ;
  unsigned short* w2f = w1f + W200SZ;
  unsigned short* w3f = w2f + W200SZ;
  unsigned short* w4f = w3f + W3SZ;
  unsigned short* wc1f = w4f + W4SZ;
  unsigned short* xcls = P0;   // aliases P0 (dead at that point)

  // single consolidated zeroing: stats x4 + bias1p + h1f (contiguous)
  hipMemsetAsync(statsA, 0, (2048 + 512 + (size_t)BDIM * 256) * sizeof(float), stream);

  // all weight conversions in one launch
  wconv_all_k<<<648, 256, 0, stream>>>(W0, W1, W2, W3, W4, w0f, w1f, w2f, w3f, w4f);

  // row sums (intra) + inter sums merged
  rowint_k<<<NROWS / 4 + 32, 256, 0, stream>>>(intra, inter, rsI, rsP);

  // block 1: nodef (fp32) -> X1 (P0)
  seg_combine_f32_k<<<BDIM, 128, 0, stream>>>(nodef, rsI, rsP, P0);

  // H = leaky(X1@W0+b0): P0 -> P1
  gemm_bf3_k<1, 0><<<dim3(128, 2), 512, 0, stream>>>(P0, w0f, b0, P1, nullptr);
  // Y1 = H@W1+b1 (+stats0): P1 -> P0
  gemm_bf3_k<0, 1><<<dim3(128, 2), 512, 0, stream>>>(P1, w1f, b1, P0, stats0);

  // block 2 (BN1 inline from stats0): P0 -> X2 (P1)
  seg_combine_bn_k<<<BDIM, 128, 0, stream>>>(P0, rsI, rsP, stats0, g1, be1, P1);

  // Y2 = leaky(X2@W2+b2) (+stats1): P1 -> P0
  gemm_bf3_k<1, 1><<<dim3(128, 2), 512, 0, stream>>>(P1, w2f, b2, P0, stats1);

  // block 3 (BN2 inline from stats1): P0 -> X3 (P1)
  seg_combine_bn_k<<<BDIM, 128, 0, stream>>>(P0, rsI, rsP, stats1, g2, be2, P1);

  // xcls = leaky(leaky(X3@W3+b3)@W4+b4): P1 -> xcls
  gemm_w34s_k<<<128, 512, 0, stream>>>(P1, w3f, w4f, b3, b4, xcls);

  // bn3d stats on xcls -> stats2; affine folded into Wc1/bias1 inline
  bn3d_stats_bf_k<<<64, 256, 0, stream>>>(xcls, stats2);
  wcls_conv_k<<<1600, 256, 0, stream>>>(Wc1, stats2, g3, wc1f);
  bias1_acc_k<<<16, 256, 0, stream>>>(Wc1, stats2, g3, be3, bias1p);

  // classifier GEMM1 (K-split atomics into pre-zeroed h1f) then tail
  gemm_cls1_k<<<dim3(8, 4, 5), 256, 0, stream>>>(xcls, wc1f, h1f);
  classifier2_k<<<BDIM / 8, 256, 0, stream>>>(h1f, bias1p, bc1, Wc2, bc2, Wc3, bc3, out);
}